// Round 9
// baseline (137.706 us; speedup 1.0000x reference)
//
#include <hip/hip_runtime.h>

#define EPS 1e-3f

// ---- ws layout (float offsets; guard gaps between same-dispatch
// producer/consumer regions) ----
#define OFF_PGAP   0         // 65536  : gap partials [256 blk][256 ch]
#define OFF_PART   81920     // 98304  : qkv split-K partials [3][32][4][256]
#define OFF_AW     196608    // 1024   : folded affine A [4][256]
#define OFF_BIAS   198656    // 16     : folded qkv bias [4][3]
#define OFF_KS     215040    // 16384  : spatial k [4][4096]
#define OFF_VS     247808    // 16384  : spatial v

#define L2E 1.4426950408889634f

// agent-scope write-through stores (to coherence point / L3); same-dispatch
// consumers use REGULAR loads whose first touch of those lines happens only
// after the counter handshake (L2 was invalidated at dispatch start, WT stores
// don't allocate in L2) — the r8-proven pattern.
__device__ __forceinline__ void st_wt(float* p, float v) {
    __hip_atomic_store(p, v, __ATOMIC_RELAXED, __HIP_MEMORY_SCOPE_AGENT);
}
__device__ __forceinline__ void st_wt2(float* p, float a, float b) {
    union { float f[2]; unsigned long long u; } x; x.f[0] = a; x.f[1] = b;
    __hip_atomic_store((unsigned long long*)p, x.u, __ATOMIC_RELAXED,
                       __HIP_MEMORY_SCOPE_AGENT);
}

// monotonic done-counters (module .data; exact per-launch group sizes make the
// modulo grouping replay-safe across graph iterations).
__device__ unsigned g_ctr1;           // +256 per launch (k_gapmid full barrier)
__device__ unsigned g_done;           // +96  per launch (matmul -> tail)
__device__ unsigned g_doneB[4 * 32];  // +64 per launch each (per-batch, padded)

// K1 (FUSED): gap partials + weight warm (256 blocks) -> 256-ticket barrier ->
// split-K qkv matmul (blocks 0..95) -> 96-ticket handshake -> last-4-finisher
// per-batch tail (part reduce, rank-1-max softmax, wp matvec, percentile, fold).
__global__ __launch_bounds__(512) void k_gapmid(
    const float* __restrict__ x,
    const float* __restrict__ cag, const float* __restrict__ cab,
    const float* __restrict__ cam, const float* __restrict__ cav,
    const float* __restrict__ wq, const float* __restrict__ wk,
    const float* __restrict__ wv, const float* __restrict__ wp,
    const float* __restrict__ bng, const float* __restrict__ bnb,
    const float* __restrict__ bnm, const float* __restrict__ bnv,
    const float* __restrict__ wqkv,
    float* __restrict__ pgap, float* __restrict__ part,
    float* __restrict__ Aw, float* __restrict__ biasW)
{
    __shared__ float smem[4360];
    __shared__ int sBatch;
    int blk = blockIdx.x;             // 0..255
    int t = threadIdx.x;              // 0..511
    int lane = t & 63, sub = t >> 6;

    // ---- gap phase (all blocks) + L3 warm ----
    {
        if (t < 256) {   // 4KB weight slice per block -> wq/wk/wv/wp into L3
            const float* wmat = (blk < 64) ? wq : (blk < 128) ? wk
                              : (blk < 192) ? wv : wp;
            float4 w4 = *(const float4*)(wmat + (size_t)(blk & 63) * 1024 + 4 * t);
            asm volatile("" :: "v"(w4.x), "v"(w4.y), "v"(w4.z), "v"(w4.w));
        }
        if (blk == 1 && t < 256) {
            float z = bng[t] + bnb[t] + bnm[t] + bnv[t];
            asm volatile("" :: "v"(z));
        }
        if (blk == 2 && t < 256) {
            float z = cag[t] + cab[t] + cam[t] + cav[t];
            asm volatile("" :: "v"(z));
        }
        float4* s4 = (float4*)smem;   // [sub=8][lane=64]
        const float* xp = x + ((size_t)blk * 64 + sub * 8) * 256 + 4 * lane;
        float4 s = make_float4(0.f, 0.f, 0.f, 0.f);
        #pragma unroll
        for (int u = 0; u < 8; ++u) {
            float4 v = *(const float4*)(xp + (size_t)u * 256);
            s.x += v.x; s.y += v.y; s.z += v.z; s.w += v.w;
        }
        s4[sub * 64 + lane] = s;
        __syncthreads();
        if (t < 64) {
            float4 o = s4[t];
            #pragma unroll
            for (int p = 1; p < 8; ++p) {
                float4 v = s4[p * 64 + t];
                o.x += v.x; o.y += v.y; o.z += v.z; o.w += v.w;
            }
            st_wt2(pgap + blk * 256 + 4 * t,     o.x, o.y);
            st_wt2(pgap + blk * 256 + 4 * t + 2, o.z, o.w);
        }
    }
    __syncthreads();                  // drain vmcnt: pgap WT at coherence point

    // ---- 256-ticket barrier; blocks >=96 exit after ticketing ----
    if (t == 0) {
        unsigned v = __hip_atomic_fetch_add(&g_ctr1, 1u, __ATOMIC_ACQ_REL,
                                            __HIP_MEMORY_SCOPE_AGENT);
        if (blk < 96) {
            unsigned target = v - (v % 256u) + 256u;
            unsigned tries = 0;
            while (__hip_atomic_load(&g_ctr1, __ATOMIC_RELAXED,
                                     __HIP_MEMORY_SCOPE_AGENT) < target) {
                __builtin_amdgcn_s_sleep(1);
                if (++tries > 8000000u) break;   // hang safety valve
            }
        }
    }
    __syncthreads();
    if (blk >= 96) return;

    // ---- matmul phase (96 blocks = 3 mats x 32 rowgroups) ----
    int m = blk / 32, g = blk % 32;
    int r0 = g * 8;
    const float* W = (m == 0) ? wq : (m == 1) ? wk : wv;
    {
        float* gpart = smem;          // [4][8][16]
        float* gn_s  = smem + 512;    // [4][8]
        float* red   = smem + 1536;   // [h*4+b][256]
        {   // gn for rows r0..r0+7, 4 batches (regular loads, first touch)
            int b = t >> 7, row = (t >> 4) & 7, p4 = t & 15;
            float s = 0.f;
            #pragma unroll
            for (int q = 0; q < 4; ++q)
                s += pgap[(size_t)(b * 64 + p4 * 4 + q) * 256 + r0 + row];
            gpart[b * 128 + row * 16 + p4] = s;
        }
        __syncthreads();
        if (t < 32) {
            int b = t >> 3, row = t & 7;
            float s = 0.f;
            #pragma unroll
            for (int p = 0; p < 16; ++p) s += gpart[b * 128 + row * 16 + p];
            float gv = s * (1.0f / 4096.0f);
            int c = r0 + row;
            float sc = cag[c] * rsqrtf(cav[c] + EPS);
            gn_s[b * 8 + row] = gv * sc + (cab[c] - cam[c] * sc);
        }
        __syncthreads();
        {   // rows split h=t>>8 (4 rows each), col c=t&255, coalesced W loads
            int c = t & 255, h = t >> 8;
            float a0 = 0.f, a1 = 0.f, a2 = 0.f, a3 = 0.f;
            #pragma unroll
            for (int rr = 0; rr < 4; ++rr) {
                int ri = h * 4 + rr;
                float w = W[(size_t)(r0 + ri) * 256 + c];
                a0 = fmaf(gn_s[0 * 8 + ri], w, a0);
                a1 = fmaf(gn_s[1 * 8 + ri], w, a1);
                a2 = fmaf(gn_s[2 * 8 + ri], w, a2);
                a3 = fmaf(gn_s[3 * 8 + ri], w, a3);
            }
            red[(h * 4 + 0) * 256 + c] = a0;
            red[(h * 4 + 1) * 256 + c] = a1;
            red[(h * 4 + 2) * 256 + c] = a2;
            red[(h * 4 + 3) * 256 + c] = a3;
        }
        __syncthreads();
        {   // combine halves, WT-store partials part[m][g][b][c]
            int b = t >> 7, c0 = (t & 127) * 2;
            float v0 = red[b * 256 + c0]     + red[(4 + b) * 256 + c0];
            float v1 = red[b * 256 + c0 + 1] + red[(4 + b) * 256 + c0 + 1];
            st_wt2(part + (size_t)((m * 32 + g) * 4 + b) * 256 + c0, v0, v1);
        }
    }
    __syncthreads();                  // drain vmcnt: part WT at coherence point
    if (t == 0) {
        unsigned v = __hip_atomic_fetch_add(&g_done, 1u, __ATOMIC_ACQ_REL,
                                            __HIP_MEMORY_SCOPE_AGENT);
        unsigned r = v % 96u;
        int batch = (int)r - 92;      // last 4 finishers take batches 0..3
        if (batch >= 0) {
            unsigned target = v - r + 96u;
            unsigned tries = 0;
            while (__hip_atomic_load(&g_done, __ATOMIC_RELAXED,
                                     __HIP_MEMORY_SCOPE_AGENT) < target) {
                __builtin_amdgcn_s_sleep(1);
                if (++tries > 8000000u) break;   // hang safety valve
            }
        }
        sBatch = batch;
    }
    __syncthreads();
    if (sBatch < 0) return;

    // ---- tail phase (one block per batch) ----
    {
        int b = sBatch;
        float* sq  = smem;            // [256]
        float* sk  = smem + 256;
        float* sv  = smem + 512;
        float* att = smem + 768;
        float* cmv = smem + 1024;
        float* Bc  = smem + 1280;
        float* red = smem + 1536;     // 2048
        float* swq = smem + 3584;     // 768
        float* sc2 = smem + 4352;     // [0]=kmx [1]=kmn [2]=t25 [3]=t26 [4]=thr

        if (t < 384) { swq[t] = wqkv[t]; swq[t + 384] = wqkv[t + 384]; }

        // reduce this batch's part slice (regular float2 loads, L3-current)
        if (t < 384) {
            int mm = t >> 7, c0 = (t & 127) * 2;
            float a0 = 0.f, a1 = 0.f;
            #pragma unroll 8
            for (int gg = 0; gg < 32; ++gg) {
                float2 v = *(const float2*)(part +
                              (size_t)((mm * 32 + gg) * 4 + b) * 256 + c0);
                a0 += v.x; a1 += v.y;
            }
            float* dst = (mm == 0) ? sq : (mm == 1) ? sk : sv;
            dst[c0] = a0; dst[c0 + 1] = a1;
        }
        __syncthreads();

        // k max/min -> exact rank-1 row max
        if (t < 64) {
            float mx = -1e30f, mn = 1e30f;
            #pragma unroll
            for (int u = 0; u < 4; ++u) {
                float v = sk[t + u * 64];
                mx = fmaxf(mx, v); mn = fminf(mn, v);
            }
            #pragma unroll
            for (int m2 = 1; m2 < 64; m2 <<= 1) {
                mx = fmaxf(mx, __shfl_xor(mx, m2, 64));
                mn = fminf(mn, __shfl_xor(mn, m2, 64));
            }
            if (t == 0) { sc2[0] = mx; sc2[1] = mn; }
        }
        __syncthreads();

        // channel softmax (exp2-direct): c = t&255, h = t>>8 covers 128-j half
        {
            int c = t & 255, h = t >> 8;
            float a = sq[c];
            float mrow = (a >= 0.f) ? a * sc2[0] : a * sc2[1];
            float a2 = a * L2E, m2 = mrow * L2E;
            const float* skp = sk + h * 128;
            const float* svp = sv + h * 128;
            float den = 0.f, num = 0.f;
            #pragma unroll 4
            for (int j = 0; j < 128; ++j) {
                float e = __builtin_amdgcn_exp2f(fmaf(a2, skp[j], -m2));
                den += e; num = fmaf(e, svp[j], num);
            }
            red[h * 256 + c] = den;
            red[512 + h * 256 + c] = num;
        }
        __syncthreads();
        if (t < 256)
            att[t] = (red[512 + t] + red[768 + t]) / (red[t] + red[256 + t]);
        __syncthreads();

        // cm = sigmoid(att @ wp): 8-way row split, float4 cols (wp L3-warm)
        {
            int rg = sub, c4 = lane * 4;
            float4 ac = make_float4(0.f, 0.f, 0.f, 0.f);
            const float* wpp = wp + (size_t)rg * 32 * 256 + c4;
            #pragma unroll 8
            for (int i = 0; i < 32; ++i) {
                float gv = att[rg * 32 + i];
                float4 w = *(const float4*)(wpp + (size_t)i * 256);
                ac.x = fmaf(gv, w.x, ac.x); ac.y = fmaf(gv, w.y, ac.y);
                ac.z = fmaf(gv, w.z, ac.z); ac.w = fmaf(gv, w.w, ac.w);
            }
            *(float4*)(red + rg * 256 + c4) = ac;
        }
        __syncthreads();
        if (t < 256) {
            float ac = 0.f;
            #pragma unroll
            for (int r = 0; r < 8; ++r) ac += red[r * 256 + t];
            cmv[t] = 1.0f / (1.0f + __expf(-ac));
        }
        __syncthreads();

        // 10th percentile (linear): s[25] + 0.5*(s[26]-s[25])
        if (t < 256) {
            float my = cmv[t];
            int rank = 0;
            for (int j = 0; j < 256; ++j) {
                float o = cmv[j];
                rank += (o < my) ? 1 : ((o == my && j < t) ? 1 : 0);
            }
            if (rank == 25) sc2[2] = my;   // unique writers (ranks = permutation)
            if (rank == 26) sc2[3] = my;
        }
        __syncthreads();
        if (t == 0) sc2[4] = sc2[2] + 0.5f * (sc2[3] - sc2[2]);
        __syncthreads();

        // fold affine A, Bc; bias = Bc @ w_qkv (regular stores; kernel-end
        // writeback publishes to next dispatch)
        if (t < 256) {
            float s2 = bng[t] * rsqrtf(bnv[t] + EPS);
            float o2 = bnb[t] - bnm[t] * s2;
            float cc = cmv[t];
            float pm = (cc > sc2[4]) ? cc : 0.f;
            Aw[b * 256 + t] = (1.f + cc) * s2 * pm;
            Bc[t] = o2 * pm;
        }
        __syncthreads();
        if (t < 3) {
            float s3 = 0.f;
            for (int ch = 0; ch < 256; ++ch)
                s3 = fmaf(Bc[ch], swq[ch * 3 + t], s3);
            biasW[b * 3 + t] = s3;
        }
    }
}

// K2 (FUSED): qkv + spatial attention. 256 blocks = (b, ic) x 512 threads.
// Phase A: block computes qkv for EXACTLY its own attention rows (pixels
// ic*64..+63 of batch b): q stays in LDS (qown), k/v WT-published.
// Per-batch 64-ticket counter barrier. Phase B: r8 attn2 body (exp2-direct),
// k/v read with regular float4 loads, q from LDS.
__global__ __launch_bounds__(512) void k_qkvattn(
    const float* __restrict__ x, const float* __restrict__ Aw,
    const float* __restrict__ wqkv, const float* __restrict__ biasW,
    float* __restrict__ ks, float* __restrict__ vs, float* __restrict__ out)
{
    __shared__ float4 skv[2048];          // (k0,v0,k1,v1) pairs for all 4096 j
    __shared__ float pden[8][64], pnum[8][64];
    __shared__ float rmax[8], rmin[8];
    __shared__ float qown[64];
    int blk = blockIdx.x;                 // 256 = b(4) * ic(64)
    int b = blk >> 6, ic = blk & 63;
    int t = threadIdx.x;                  // 0..511
    int lane = t & 63, sub = t >> 6;
    int sl = lane & 31, half = lane >> 5;
    int base = b * 4096;

    // ---- phase A: qkv for own 64 pixels ----
    {
        union { float4 v4[6]; float f[24]; } W;   // rows sl*8..+7 x 3
        #pragma unroll
        for (int i = 0; i < 6; ++i)
            W.v4[i] = *(const float4*)(wqkv + 24 * sl + 4 * i);
        float4 a0 = *(const float4*)(Aw + b * 256 + sl * 8);
        float4 a1 = *(const float4*)(Aw + b * 256 + sl * 8 + 4);
        float bq = biasW[b * 3 + 0];      // uniform -> broadcast
        float bk = biasW[b * 3 + 1];
        float bv = biasW[b * 3 + 2];
        #pragma unroll
        for (int it = 0; it < 4; ++it) {
            int local = sub * 8 + it * 2 + half;
            int pix = base + ic * 64 + local;
            const float* xp = x + (size_t)pix * 256 + sl * 8;
            float4 xv0 = *(const float4*)(xp);
            float4 xv1 = *(const float4*)(xp + 4);
            float tt0 = xv0.x * a0.x, tt1 = xv0.y * a0.y;
            float tt2 = xv0.z * a0.z, tt3 = xv0.w * a0.w;
            float tt4 = xv1.x * a1.x, tt5 = xv1.y * a1.y;
            float tt6 = xv1.z * a1.z, tt7 = xv1.w * a1.w;
            float q = tt0 * W.f[0] + tt1 * W.f[3] + tt2 * W.f[6] + tt3 * W.f[9]
                    + tt4 * W.f[12] + tt5 * W.f[15] + tt6 * W.f[18] + tt7 * W.f[21];
            float k = tt0 * W.f[1] + tt1 * W.f[4] + tt2 * W.f[7] + tt3 * W.f[10]
                    + tt4 * W.f[13] + tt5 * W.f[16] + tt6 * W.f[19] + tt7 * W.f[22];
            float v = tt0 * W.f[2] + tt1 * W.f[5] + tt2 * W.f[8] + tt3 * W.f[11]
                    + tt4 * W.f[14] + tt5 * W.f[17] + tt6 * W.f[20] + tt7 * W.f[23];
            #pragma unroll
            for (int m2 = 1; m2 < 32; m2 <<= 1) {   // reduce within 32-lane group
                q += __shfl_xor(q, m2, 64);
                k += __shfl_xor(k, m2, 64);
                v += __shfl_xor(v, m2, 64);
            }
            if (sl == 0) {
                qown[local] = q + bq;
                st_wt(ks + pix, k + bk);
                st_wt(vs + pix, v + bv);
            }
        }
    }
    __syncthreads();                      // drain vmcnt + publish qown
    if (t == 0) {
        unsigned v = __hip_atomic_fetch_add(&g_doneB[b * 32], 1u,
                                            __ATOMIC_ACQ_REL,
                                            __HIP_MEMORY_SCOPE_AGENT);
        unsigned target = v - (v % 64u) + 64u;
        unsigned tries = 0;
        while (__hip_atomic_load(&g_doneB[b * 32], __ATOMIC_RELAXED,
                                 __HIP_MEMORY_SCOPE_AGENT) < target) {
            __builtin_amdgcn_s_sleep(1);
            if (++tries > 8000000u) break;    // hang safety valve
        }
    }
    __syncthreads();

    // ---- phase B: spatial attention + output ----
    {
        const float4* k4 = (const float4*)(ks + base);   // regular (first touch)
        const float4* v4 = (const float4*)(vs + base);
        float kmx = -1e30f, kmn = 1e30f;
        #pragma unroll
        for (int u = 0; u < 2; ++u) {
            int i = t + u * 512;              // 0..1023 float4 rows
            float4 kk = k4[i], vv = v4[i];
            skv[i * 2]     = make_float4(kk.x, vv.x, kk.y, vv.y);
            skv[i * 2 + 1] = make_float4(kk.z, vv.z, kk.w, vv.w);
            kmx = fmaxf(kmx, fmaxf(fmaxf(kk.x, kk.y), fmaxf(kk.z, kk.w)));
            kmn = fminf(kmn, fminf(fminf(kk.x, kk.y), fminf(kk.z, kk.w)));
        }
        #pragma unroll
        for (int m2 = 1; m2 < 64; m2 <<= 1) {
            kmx = fmaxf(kmx, __shfl_xor(kmx, m2, 64));
            kmn = fminf(kmn, __shfl_xor(kmn, m2, 64));
        }
        if (lane == 0) { rmax[sub] = kmx; rmin[sub] = kmn; }
        __syncthreads();
        float mx = rmax[0], mn = rmin[0];
        #pragma unroll
        for (int s = 1; s < 8; ++s) { mx = fmaxf(mx, rmax[s]); mn = fminf(mn, rmin[s]); }

        float a = qown[lane];
        float mrow = (a >= 0.f) ? a * mx : a * mn;   // exact global row max
        float a2 = a * L2E, m2v = mrow * L2E;
        float den0 = 0.f, num0 = 0.f, den1 = 0.f, num1 = 0.f;
        const float4* sp = skv + sub * 256;   // this wave's 512-j slice
        #pragma unroll 4
        for (int j = 0; j < 256; ++j) {
            float4 kv = sp[j];                // uniform addr -> broadcast
            float e0 = __builtin_amdgcn_exp2f(fmaf(a2, kv.x, -m2v));
            float e1 = __builtin_amdgcn_exp2f(fmaf(a2, kv.z, -m2v));
            den0 += e0; num0 = fmaf(e0, kv.y, num0);
            den1 += e1; num1 = fmaf(e1, kv.w, num1);
        }
        pden[sub][lane] = den0 + den1;
        pnum[sub][lane] = num0 + num1;
        __syncthreads();
        if (t < 64) {
            float den = 0.f, num = 0.f;
            #pragma unroll
            for (int s = 0; s < 8; ++s) { den += pden[s][t]; num += pnum[s][t]; }
            int r = ic * 64 + t;
            float vrow = (r & 1) ? skv[r >> 1].w : skv[r >> 1].y;   // v from LDS
            out[base + r] = vrow + num / den;
        }
    }
}

extern "C" void kernel_launch(void* const* d_in, const int* in_sizes, int n_in,
                              void* d_out, int out_size, void* d_ws, size_t ws_size,
                              hipStream_t stream) {
    const float* x    = (const float*)d_in[0];
    const float* cag  = (const float*)d_in[1];
    const float* cab  = (const float*)d_in[2];
    const float* cam  = (const float*)d_in[3];
    const float* cav  = (const float*)d_in[4];
    const float* wq   = (const float*)d_in[5];
    const float* wk   = (const float*)d_in[6];
    const float* wv   = (const float*)d_in[7];
    const float* wp   = (const float*)d_in[8];
    const float* bng  = (const float*)d_in[9];
    const float* bnb  = (const float*)d_in[10];
    const float* bnm  = (const float*)d_in[11];
    const float* bnv  = (const float*)d_in[12];
    const float* wqkv = (const float*)d_in[13];

    float* ws   = (float*)d_ws;
    float* pgap = ws + OFF_PGAP;
    float* part = ws + OFF_PART;
    float* Aw   = ws + OFF_AW;
    float* bias = ws + OFF_BIAS;
    float* ks   = ws + OFF_KS;
    float* vs   = ws + OFF_VS;

    k_gapmid<<<dim3(256), dim3(512), 0, stream>>>(x, cag, cab, cam, cav,
                                                  wq, wk, wv, wp,
                                                  bng, bnb, bnm, bnv, wqkv,
                                                  pgap, part, Aw, bias);
    k_qkvattn<<<dim3(256), dim3(512), 0, stream>>>(x, Aw, wqkv, bias,
                                                   ks, vs, (float*)d_out);
}

// Round 10
// 125.870 us; speedup vs baseline: 1.0940x; 1.0940x over previous
//
#include <hip/hip_runtime.h>

#define EPS 1e-3f

// ---- ws layout (float offsets; guard gaps: pgap/part are produced+consumed in
// the SAME dispatch (fused kernel), so keep regions line-separated) ----
#define OFF_PGAP   0         // 65536  : gap partials [256 blk][256 ch]
#define OFF_PART   81920     // 98304  : qkv split-K partials [3][32][4][256]
#define OFF_AW     196608    // 1024   : folded affine A [4][256]
#define OFF_BIAS   198656    // 16     : folded qkv bias [4][3]
#define OFF_QS     215040    // 16384  : spatial q [4][4096]
#define OFF_KS     231424    // 16384  : spatial k
#define OFF_VS     247808    // 16384  : spatial v

#define L2E 1.4426950408889634f

// agent-scope write-through store (to coherence point / L3); consumers in the
// SAME dispatch read with regular loads (their L2 was invalidated at dispatch
// start and first-touches these lines only after the counter handshake).
__device__ __forceinline__ void st_wt2(float* p, float a, float b) {
    union { float f[2]; unsigned long long u; } x; x.f[0] = a; x.f[1] = b;
    __hip_atomic_store((unsigned long long*)p, x.u, __ATOMIC_RELAXED,
                       __HIP_MEMORY_SCOPE_AGENT);
}

// monotonic done-counter for the fused kernel (module .data, zero-init once per
// process; modulo-96 logic is replay-safe across graph iterations).
__device__ unsigned g_done;

// K1: gap partial sums, float4 loads, 8 waves x 8 pixels. 256 blocks x 512 thr.
// Side duty: warm the 1MB of attention weights + bn/ca params into L3.
__global__ __launch_bounds__(512) void k_gap(
    const float* __restrict__ x,
    const float* __restrict__ wq, const float* __restrict__ wk,
    const float* __restrict__ wv, const float* __restrict__ wp,
    const float* __restrict__ bng, const float* __restrict__ bnb,
    const float* __restrict__ bnm, const float* __restrict__ bnv,
    const float* __restrict__ cag, const float* __restrict__ cab,
    const float* __restrict__ cam, const float* __restrict__ cav,
    float* __restrict__ pgap)
{
    __shared__ float4 s4[512];        // [sub=8][lane=64]
    int blk = blockIdx.x;             // 0..255 ; pixel base = blk*64
    int t = threadIdx.x;              // 0..511
    int lane = t & 63, sub = t >> 6;

    if (t < 256) {   // 4KB weight slice per block -> all of wq/wk/wv/wp into L3
        const float* wmat = (blk < 64) ? wq : (blk < 128) ? wk
                          : (blk < 192) ? wv : wp;
        float4 w4 = *(const float4*)(wmat + (size_t)(blk & 63) * 1024 + 4 * t);
        asm volatile("" :: "v"(w4.x), "v"(w4.y), "v"(w4.z), "v"(w4.w));
    }
    if (blk == 1 && t < 256) {
        float z = bng[t] + bnb[t] + bnm[t] + bnv[t];
        asm volatile("" :: "v"(z));
    }
    if (blk == 2 && t < 256) {
        float z = cag[t] + cab[t] + cam[t] + cav[t];
        asm volatile("" :: "v"(z));
    }

    const float* xp = x + ((size_t)blk * 64 + sub * 8) * 256 + 4 * lane;
    float4 s = make_float4(0.f, 0.f, 0.f, 0.f);
    #pragma unroll
    for (int u = 0; u < 8; ++u) {
        float4 v = *(const float4*)(xp + (size_t)u * 256);
        s.x += v.x; s.y += v.y; s.z += v.z; s.w += v.w;
    }
    s4[sub * 64 + lane] = s;
    __syncthreads();
    if (t < 64) {
        float4 o = s4[t];
        #pragma unroll
        for (int p = 1; p < 8; ++p) {
            float4 v = s4[p * 64 + t];
            o.x += v.x; o.y += v.y; o.z += v.z; o.w += v.w;
        }
        *(float4*)(pgap + blk * 256 + 4 * t) = o;
    }
}

// K2 (FUSED): split-K qkv matmul + middle-stage tail. 96 blocks x 512 threads.
// Matmul phase: 3 mats x 32 rowgroups; WT-store partials; fetch_add done-ctr.
// The last FOUR finishers (v%96 in 92..95) each take batch (v%96-92), spin
// until all 96 arrived, then run the per-batch tail: part reduce -> channel
// softmax (exact rank-1 max, exp2-direct) -> wp matvec -> sigmoid ->
// percentile -> folded affine A, bias.
__global__ __launch_bounds__(512) void k_qkvmid(
    const float* __restrict__ pgap,
    const float* __restrict__ cag, const float* __restrict__ cab,
    const float* __restrict__ cam, const float* __restrict__ cav,
    const float* __restrict__ wq, const float* __restrict__ wk,
    const float* __restrict__ wv, const float* __restrict__ wp,
    const float* __restrict__ bng, const float* __restrict__ bnb,
    const float* __restrict__ bnm, const float* __restrict__ bnv,
    const float* __restrict__ wqkv,
    float* __restrict__ part, float* __restrict__ Aw, float* __restrict__ biasW)
{
    __shared__ float smem[4360];
    __shared__ int sBatch;
    int blk = blockIdx.x;
    int m = blk / 32, g = blk % 32;   // matrix, rowgroup
    int r0 = g * 8;
    int t = threadIdx.x;
    int lane = t & 63, sub = t >> 6;
    const float* W = (m == 0) ? wq : (m == 1) ? wk : wv;

    // ---- matmul phase ----
    {
        float* gpart = smem;          // [4][8][16]
        float* gn_s  = smem + 512;    // [4][8]
        float* red   = smem + 1536;   // [h*4+b][256]
        {   // gn for rows r0..r0+7, 4 batches
            int b = t >> 7, row = (t >> 4) & 7, p4 = t & 15;
            float s = 0.f;
            #pragma unroll
            for (int q = 0; q < 4; ++q)
                s += pgap[(size_t)(b * 64 + p4 * 4 + q) * 256 + r0 + row];
            gpart[b * 128 + row * 16 + p4] = s;
        }
        __syncthreads();
        if (t < 32) {
            int b = t >> 3, row = t & 7;
            float s = 0.f;
            #pragma unroll
            for (int p = 0; p < 16; ++p) s += gpart[b * 128 + row * 16 + p];
            float gv = s * (1.0f / 4096.0f);
            int c = r0 + row;
            float sc = cag[c] * rsqrtf(cav[c] + EPS);
            gn_s[b * 8 + row] = gv * sc + (cab[c] - cam[c] * sc);
        }
        __syncthreads();
        {   // rows split h=t>>8 (4 rows each), col c=t&255, coalesced W loads
            int c = t & 255, h = t >> 8;
            float a0 = 0.f, a1 = 0.f, a2 = 0.f, a3 = 0.f;
            #pragma unroll
            for (int rr = 0; rr < 4; ++rr) {
                int ri = h * 4 + rr;
                float w = W[(size_t)(r0 + ri) * 256 + c];
                a0 = fmaf(gn_s[0 * 8 + ri], w, a0);
                a1 = fmaf(gn_s[1 * 8 + ri], w, a1);
                a2 = fmaf(gn_s[2 * 8 + ri], w, a2);
                a3 = fmaf(gn_s[3 * 8 + ri], w, a3);
            }
            red[(h * 4 + 0) * 256 + c] = a0;
            red[(h * 4 + 1) * 256 + c] = a1;
            red[(h * 4 + 2) * 256 + c] = a2;
            red[(h * 4 + 3) * 256 + c] = a3;
        }
        __syncthreads();
        {   // combine halves, WT-store partials part[m][g][b][c]
            int b = t >> 7, c0 = (t & 127) * 2;
            float v0 = red[b * 256 + c0]     + red[(4 + b) * 256 + c0];
            float v1 = red[b * 256 + c0 + 1] + red[(4 + b) * 256 + c0 + 1];
            st_wt2(part + (size_t)((m * 32 + g) * 4 + b) * 256 + c0, v0, v1);
        }
    }
    __syncthreads();                  // drain vmcnt: WT stores at coherence point
    if (t == 0) {
        unsigned v = __hip_atomic_fetch_add(&g_done, 1u, __ATOMIC_ACQ_REL,
                                            __HIP_MEMORY_SCOPE_AGENT);
        unsigned r = v % 96u;
        int batch = (int)r - 92;      // last 4 finishers take batches 0..3
        if (batch >= 0) {
            unsigned target = v - r + 96u;
            unsigned tries = 0;
            while (__hip_atomic_load(&g_done, __ATOMIC_RELAXED,
                                     __HIP_MEMORY_SCOPE_AGENT) < target) {
                __builtin_amdgcn_s_sleep(1);
                if (++tries > 8000000u) break;   // hang safety valve
            }
        }
        sBatch = batch;
    }
    __syncthreads();
    if (sBatch < 0) return;

    // ---- tail phase (one block per batch) ----
    {
        int b = sBatch;
        float* sq  = smem;            // [256]
        float* sk  = smem + 256;
        float* sv  = smem + 512;
        float* att = smem + 768;
        float* cmv = smem + 1024;
        float* Bc  = smem + 1280;
        float* red = smem + 1536;     // 2048
        float* swq = smem + 3584;     // 768
        float* sc2 = smem + 4352;     // [0]=kmx [1]=kmn [2]=t25 [3]=t26 [4]=thr

        if (t < 384) { swq[t] = wqkv[t]; swq[t + 384] = wqkv[t + 384]; }

        // reduce this batch's part slice (regular float2 loads, L3-current)
        if (t < 384) {
            int mm = t >> 7, c0 = (t & 127) * 2;
            float a0 = 0.f, a1 = 0.f;
            #pragma unroll 8
            for (int gg = 0; gg < 32; ++gg) {
                float2 v = *(const float2*)(part +
                              (size_t)((mm * 32 + gg) * 4 + b) * 256 + c0);
                a0 += v.x; a1 += v.y;
            }
            float* dst = (mm == 0) ? sq : (mm == 1) ? sk : sv;
            dst[c0] = a0; dst[c0 + 1] = a1;
        }
        __syncthreads();

        // k max/min -> exact rank-1 row max
        if (t < 64) {
            float mx = -1e30f, mn = 1e30f;
            #pragma unroll
            for (int u = 0; u < 4; ++u) {
                float v = sk[t + u * 64];
                mx = fmaxf(mx, v); mn = fminf(mn, v);
            }
            #pragma unroll
            for (int m2 = 1; m2 < 64; m2 <<= 1) {
                mx = fmaxf(mx, __shfl_xor(mx, m2, 64));
                mn = fminf(mn, __shfl_xor(mn, m2, 64));
            }
            if (t == 0) { sc2[0] = mx; sc2[1] = mn; }
        }
        __syncthreads();

        // channel softmax (exp2-direct): c = t&255, h = t>>8 covers a 128-j half
        {
            int c = t & 255, h = t >> 8;
            float a = sq[c];
            float mrow = (a >= 0.f) ? a * sc2[0] : a * sc2[1];
            float a2 = a * L2E, m2 = mrow * L2E;
            const float* skp = sk + h * 128;
            const float* svp = sv + h * 128;
            float den = 0.f, num = 0.f;
            #pragma unroll 4
            for (int j = 0; j < 128; ++j) {
                float e = __builtin_amdgcn_exp2f(fmaf(a2, skp[j], -m2));
                den += e; num = fmaf(e, svp[j], num);
            }
            red[h * 256 + c] = den;
            red[512 + h * 256 + c] = num;
        }
        __syncthreads();
        if (t < 256)
            att[t] = (red[512 + t] + red[768 + t]) / (red[t] + red[256 + t]);
        __syncthreads();

        // cm = sigmoid(att @ wp): 8-way row split, float4 cols (wp L3-warm)
        {
            int rg = sub, c4 = lane * 4;
            float4 ac = make_float4(0.f, 0.f, 0.f, 0.f);
            const float* wpp = wp + (size_t)rg * 32 * 256 + c4;
            #pragma unroll 8
            for (int i = 0; i < 32; ++i) {
                float gv = att[rg * 32 + i];
                float4 w = *(const float4*)(wpp + (size_t)i * 256);
                ac.x = fmaf(gv, w.x, ac.x); ac.y = fmaf(gv, w.y, ac.y);
                ac.z = fmaf(gv, w.z, ac.z); ac.w = fmaf(gv, w.w, ac.w);
            }
            *(float4*)(red + rg * 256 + c4) = ac;
        }
        __syncthreads();
        if (t < 256) {
            float ac = 0.f;
            #pragma unroll
            for (int r = 0; r < 8; ++r) ac += red[r * 256 + t];
            cmv[t] = 1.0f / (1.0f + __expf(-ac));
        }
        __syncthreads();

        // 10th percentile (linear): s[25] + 0.5*(s[26]-s[25])
        if (t < 256) {
            float my = cmv[t];
            int rank = 0;
            for (int j = 0; j < 256; ++j) {
                float o = cmv[j];
                rank += (o < my) ? 1 : ((o == my && j < t) ? 1 : 0);
            }
            if (rank == 25) sc2[2] = my;   // unique writers (ranks = permutation)
            if (rank == 26) sc2[3] = my;
        }
        __syncthreads();
        if (t == 0) sc2[4] = sc2[2] + 0.5f * (sc2[3] - sc2[2]);
        __syncthreads();

        // fold affine A, Bc; bias = Bc @ w_qkv (plain stores: kernel-end
        // writeback makes them visible to the next dispatch)
        if (t < 256) {
            float s2 = bng[t] * rsqrtf(bnv[t] + EPS);
            float o2 = bnb[t] - bnm[t] * s2;
            float cc = cmv[t];
            float pm = (cc > sc2[4]) ? cc : 0.f;
            Aw[b * 256 + t] = (1.f + cc) * s2 * pm;
            Bc[t] = o2 * pm;
        }
        __syncthreads();
        if (t < 3) {
            float s3 = 0.f;
            for (int ch = 0; ch < 256; ++ch)
                s3 = fmaf(Bc[ch], swq[ch * 3 + t], s3);
            biasW[b * 3 + t] = s3;
        }
    }
}

// K3: qkv = (x*A + B) @ w_qkv. 32 lanes per pixel (2 px per wave-iter):
// 5-level shuffle reduce instead of 6 -> 7.5 shuffles/pixel vs 18.
// 512 blocks x 256 threads. x is L3-resident after K1.
__global__ __launch_bounds__(256) void k_qkv(
    const float* __restrict__ x, const float* __restrict__ A,
    const float* __restrict__ wqkv, const float* __restrict__ bias,
    float* __restrict__ qs, float* __restrict__ ks, float* __restrict__ vs)
{
    int t = threadIdx.x;
    int lane = t & 63;
    int sl = lane & 31;               // sub-lane within 32-group
    int half = lane >> 5;             // pixel selector
    int wid = (blockIdx.x * 256 + t) >> 6;   // 0..2047 (wave-uniform)
    union { float4 v4[6]; float f[24]; } W;  // rows sl*8..sl*8+7 x 3
    #pragma unroll
    for (int i = 0; i < 6; ++i)
        W.v4[i] = *(const float4*)(wqkv + 24 * sl + 4 * i);
    #pragma unroll
    for (int b = 0; b < 4; ++b) {
        int pix = b * 4096 + wid * 2 + half;
        const float* xp = x + (size_t)pix * 256 + sl * 8;
        float4 xv0 = *(const float4*)(xp);
        float4 xv1 = *(const float4*)(xp + 4);
        float4 a0 = *(const float4*)(A + b * 256 + sl * 8);
        float4 a1 = *(const float4*)(A + b * 256 + sl * 8 + 4);
        float bq = bias[b * 3 + 0];   // uniform -> broadcast
        float bk = bias[b * 3 + 1];
        float bv = bias[b * 3 + 2];
        float tt0 = xv0.x * a0.x, tt1 = xv0.y * a0.y;
        float tt2 = xv0.z * a0.z, tt3 = xv0.w * a0.w;
        float tt4 = xv1.x * a1.x, tt5 = xv1.y * a1.y;
        float tt6 = xv1.z * a1.z, tt7 = xv1.w * a1.w;
        float q = tt0 * W.f[0] + tt1 * W.f[3] + tt2 * W.f[6] + tt3 * W.f[9]
                + tt4 * W.f[12] + tt5 * W.f[15] + tt6 * W.f[18] + tt7 * W.f[21];
        float k = tt0 * W.f[1] + tt1 * W.f[4] + tt2 * W.f[7] + tt3 * W.f[10]
                + tt4 * W.f[13] + tt5 * W.f[16] + tt6 * W.f[19] + tt7 * W.f[22];
        float v = tt0 * W.f[2] + tt1 * W.f[5] + tt2 * W.f[8] + tt3 * W.f[11]
                + tt4 * W.f[14] + tt5 * W.f[17] + tt6 * W.f[20] + tt7 * W.f[23];
        #pragma unroll
        for (int m2 = 1; m2 < 32; m2 <<= 1) {   // reduce within 32-lane group
            q += __shfl_xor(q, m2, 64);
            k += __shfl_xor(k, m2, 64);
            v += __shfl_xor(v, m2, 64);
        }
        if (sl == 0) {
            qs[pix] = q + bq; ks[pix] = k + bk; vs[pix] = v + bv;
        }
    }
}

// K4: fused spatial attention + output. 256 blocks = (b, 64 row-chunks) x 512.
// Full batch K/V (32 KB) LDS-resident; global k-max/min -> exact row max;
// exp2-direct softmax (log2e folded into a,m once per row); direct out.
__global__ __launch_bounds__(512) void k_attn2(
    const float* __restrict__ qs, const float* __restrict__ ks,
    const float* __restrict__ vs, float* __restrict__ out)
{
    __shared__ float4 skv[2048];          // (k0,v0,k1,v1) pairs for all 4096 j
    __shared__ float pden[8][64], pnum[8][64];
    __shared__ float rmax[8], rmin[8];
    int blk = blockIdx.x;                 // 256 = b(4) * ic(64)
    int b = blk >> 6, ic = blk & 63;
    int t = threadIdx.x;                  // 0..511
    int lane = t & 63, sub = t >> 6;      // sub = wave id (wave-uniform)
    int base = b * 4096;

    const float4* k4 = (const float4*)(ks + base);
    const float4* v4 = (const float4*)(vs + base);
    float kmx = -1e30f, kmn = 1e30f;
    #pragma unroll
    for (int u = 0; u < 2; ++u) {
        int i = t + u * 512;              // 0..1023 float4 rows
        float4 kk = k4[i], vv = v4[i];
        skv[i * 2]     = make_float4(kk.x, vv.x, kk.y, vv.y);
        skv[i * 2 + 1] = make_float4(kk.z, vv.z, kk.w, vv.w);
        kmx = fmaxf(kmx, fmaxf(fmaxf(kk.x, kk.y), fmaxf(kk.z, kk.w)));
        kmn = fminf(kmn, fminf(fminf(kk.x, kk.y), fminf(kk.z, kk.w)));
    }
    #pragma unroll
    for (int m2 = 1; m2 < 64; m2 <<= 1) {
        kmx = fmaxf(kmx, __shfl_xor(kmx, m2, 64));
        kmn = fminf(kmn, __shfl_xor(kmn, m2, 64));
    }
    if (lane == 0) { rmax[sub] = kmx; rmin[sub] = kmn; }
    __syncthreads();
    float mx = rmax[0], mn = rmin[0];
    #pragma unroll
    for (int s = 1; s < 8; ++s) { mx = fmaxf(mx, rmax[s]); mn = fminf(mn, rmin[s]); }

    int row = ic * 64 + lane;
    float a = qs[base + row];
    float mrow = (a >= 0.f) ? a * mx : a * mn;   // exact global row max (rank-1)
    float a2 = a * L2E, m2v = mrow * L2E;
    float den0 = 0.f, num0 = 0.f, den1 = 0.f, num1 = 0.f;
    const float4* sp = skv + sub * 256;       // this wave's 512-j slice
    #pragma unroll 4
    for (int j = 0; j < 256; ++j) {
        float4 kv = sp[j];                    // uniform addr -> broadcast
        float e0 = __builtin_amdgcn_exp2f(fmaf(a2, kv.x, -m2v));
        float e1 = __builtin_amdgcn_exp2f(fmaf(a2, kv.z, -m2v));
        den0 += e0; num0 = fmaf(e0, kv.y, num0);
        den1 += e1; num1 = fmaf(e1, kv.w, num1);
    }
    pden[sub][lane] = den0 + den1;
    pnum[sub][lane] = num0 + num1;
    __syncthreads();
    if (t < 64) {
        float den = 0.f, num = 0.f;
        #pragma unroll
        for (int s = 0; s < 8; ++s) { den += pden[s][t]; num += pnum[s][t]; }
        int r = ic * 64 + t;
        float vrow = (r & 1) ? skv[r >> 1].w : skv[r >> 1].y;   // v from LDS
        out[base + r] = vrow + num / den;
    }
}

extern "C" void kernel_launch(void* const* d_in, const int* in_sizes, int n_in,
                              void* d_out, int out_size, void* d_ws, size_t ws_size,
                              hipStream_t stream) {
    const float* x    = (const float*)d_in[0];
    const float* cag  = (const float*)d_in[1];
    const float* cab  = (const float*)d_in[2];
    const float* cam  = (const float*)d_in[3];
    const float* cav  = (const float*)d_in[4];
    const float* wq   = (const float*)d_in[5];
    const float* wk   = (const float*)d_in[6];
    const float* wv   = (const float*)d_in[7];
    const float* wp   = (const float*)d_in[8];
    const float* bng  = (const float*)d_in[9];
    const float* bnb  = (const float*)d_in[10];
    const float* bnm  = (const float*)d_in[11];
    const float* bnv  = (const float*)d_in[12];
    const float* wqkv = (const float*)d_in[13];

    float* ws   = (float*)d_ws;
    float* pgap = ws + OFF_PGAP;
    float* part = ws + OFF_PART;
    float* Aw   = ws + OFF_AW;
    float* bias = ws + OFF_BIAS;
    float* qs   = ws + OFF_QS;
    float* ks   = ws + OFF_KS;
    float* vs   = ws + OFF_VS;

    k_gap<<<dim3(256), dim3(512), 0, stream>>>(x, wq, wk, wv, wp,
                                               bng, bnb, bnm, bnv,
                                               cag, cab, cam, cav, pgap);
    k_qkvmid<<<dim3(96), dim3(512), 0, stream>>>(pgap, cag, cab, cam, cav,
                                                 wq, wk, wv, wp,
                                                 bng, bnb, bnm, bnv, wqkv,
                                                 part, Aw, bias);
    k_qkv<<<dim3(512), dim3(256), 0, stream>>>(x, Aw, wqkv, bias, qs, ks, vs);
    k_attn2<<<dim3(256), dim3(512), 0, stream>>>(qs, ks, vs, (float*)d_out);
}